// Round 1
// baseline (289.317 us; speedup 1.0000x reference)
//
#include <hip/hip_runtime.h>

// B=256 batches, N=128 neurons, E = 4N = 512. Out: ydot (B*E) | J (B*E*E).
// Single fused kernel: block = one batch (256 blocks, 512 threads, 1 block/CU).
// Phase 1: physics + reductions into LDS. Phase 2: stream the batch's 1 MB
// J-slab as 128 x 8KB fully-linear bursts (one global_store_dwordx4 per lane
// per iteration, all values hoisted/LDS-resident).
#define BATCH 256
#define NN    128
#define EDIM  512

typedef float vf4 __attribute__((ext_vector_type(4)));

__global__ __launch_bounds__(512) void hh_fused(
    const float* __restrict__ y,     const float* __restrict__ Ic,
    const float* __restrict__ C,     const float* __restrict__ g_Na,
    const float* __restrict__ E_Na,  const float* __restrict__ g_K,
    const float* __restrict__ E_K,   const float* __restrict__ g_L,
    const float* __restrict__ E_L,   const float* __restrict__ m_inf,
    const float* __restrict__ tau_m, const float* __restrict__ h_inf,
    const float* __restrict__ tau_h, const float* __restrict__ n_inf,
    const float* __restrict__ tau_n, const float* __restrict__ g_C,
    float* __restrict__ ydot_out,    vf4* __restrict__ J)
{
    __shared__ float  sInvC[NN];
    __shared__ float  sW[NN];
    __shared__ float  sRed[NN];
    __shared__ float  sS;
    __shared__ float4 sJV[NN];        // (jvv, jvm, jvh, jvn) per neuron
    __shared__ float  sNit[3 * NN];   // -1/tau_m | -1/tau_h | -1/tau_n

    const int b  = blockIdx.x;
    const int t  = threadIdx.x;
    const int i  = t >> 2;
    const int jq = t & 3;

    if (t < NN) {
        const float ic = 1.0f / C[t];
        sInvC[t] = ic;
        sW[t] = y[(size_t)b * EDIM + 4 * t] * ic;   // V_j * invC_j
    } else {
        const int k = t - NN;                        // 0..383, wave-uniform select
        const float* tau = (k < NN) ? tau_m : (k < 2 * NN ? tau_h : tau_n);
        sNit[k] = -1.0f / tau[k & (NN - 1)];
    }
    __syncthreads();

    // Partial dots over j = jq*32 .. jq*32+31 (8 independent float4 loads)
    float rowS = 0.f, dotW = 0.f;
    const float4* grow = (const float4*)(g_C + (i << 7) + (jq << 5));
#pragma unroll
    for (int j4 = 0; j4 < 8; ++j4) {
        const float4 g = grow[j4];
        const int j = (jq << 5) + j4 * 4;
        rowS += g.x * sInvC[j] + g.y * sInvC[j + 1] + g.z * sInvC[j + 2] + g.w * sInvC[j + 3];
        dotW += g.x * sW[j]    + g.y * sW[j + 1]    + g.z * sW[j + 2]    + g.w * sW[j + 3];
    }
    rowS += __shfl_xor(rowS, 1);  rowS += __shfl_xor(rowS, 2);
    dotW += __shfl_xor(dotW, 1);  dotW += __shfl_xor(dotW, 2);

    if (jq == 0) sRed[i] = rowS;
    __syncthreads();
    if (t < 64) {   // S = sum_i rowS[i]
        float v = sRed[t] + sRed[t + 64];
        v += __shfl_xor(v, 1);  v += __shfl_xor(v, 2);  v += __shfl_xor(v, 4);
        v += __shfl_xor(v, 8);  v += __shfl_xor(v, 16); v += __shfl_xor(v, 32);
        if (t == 0) sS = v;
    }
    __syncthreads();

    if (jq == 0) {
        const float S = sS;
        const float4 yv = ((const float4*)(y + (size_t)b * EDIM))[i];
        const float V = yv.x, m = yv.y, h = yv.z, n = yv.w;
        const float invC = sInvC[i];
        const float dV = V * rowS - dotW;

        const float m2 = m * m, m3 = m2 * m;
        const float n2 = n * n, n3 = n2 * n, n4 = n3 * n;
        const float gna = g_Na[i], ena = E_Na[i];
        const float gk  = g_K[i],  ek  = E_K[i];
        const float gl  = g_L[i],  el  = E_L[i];

        const float Vdot = invC * (-gna * m3 * h * (V - ena)
                                   - gk * n4 * (V - ek)
                                   - gl * (V - el)
                                   + Ic[b]) + dV;
        const float itm = -sNit[i];           // +1/tau_m
        const float ith = -sNit[NN + i];
        const float itn = -sNit[2 * NN + i];

        ((float4*)(ydot_out + (size_t)b * EDIM))[i] =
            make_float4(Vdot, (m_inf[i] - m) * itm, (h_inf[i] - h) * ith,
                        (n_inf[i] - n) * itn);

        const float jvv = invC * (-gl - gna * h * m3 - gk * n4) + S;
        const float jvm = -invC * (3.0f * gna * h * m2 * (V - ena));
        const float jvh = -invC * (gna * m3 * (V - ena));
        const float jvn = -invC * (4.0f * gk * n3 * (V - ek));
        sJV[i] = make_float4(jvv, jvm, jvh, jvn);
    }
    __syncthreads();

    // ---- Phase 2: stream J rows b*512 .. b*512+511 (1 MB, fully linear) ----
    // thread t -> eq-type a = t>>7 (wave-uniform), float4-column q = t&127.
    // iteration r writes rows 4r..4r+3: per-iter the block emits one
    // contiguous 8 KB burst.  vf4 index of (row, q) = (b*512 + 4r + a)*128 + q.
    const int a = t >> 7;
    const int q = t & 127;
    vf4* __restrict__ Jp = J + ((size_t)b * EDIM + a) * (EDIM / 4) + q;

    if (a == 0) {
        const float  icq = sInvC[q];
        const float4 jvq = sJV[q];
        const float* __restrict__ gq = g_C + q;
#pragma unroll 4
        for (int r = 0; r < NN; ++r) {
            const float gv = gq[r << 7];           // g_C[r][q], coalesced 512B/iter
            vf4 v;
            v.x = -gv * icq;
            v.y = 0.f; v.z = 0.f; v.w = 0.f;
            if (r == q) { v.x += jvq.x; v.y = jvq.y; v.z = jvq.z; v.w = jvq.w; }
            Jp[(size_t)r * EDIM] = v;              // 4-row stride = 512 vf4
        }
    } else {
        const float d = sNit[((a - 1) << 7) + q];
        vf4 dv = {0.f, 0.f, 0.f, 0.f};
        if (a == 1) dv.y = d; else if (a == 2) dv.z = d; else dv.w = d;
#pragma unroll 4
        for (int r = 0; r < NN; ++r) {
            vf4 v = {0.f, 0.f, 0.f, 0.f};
            if (r == q) v = dv;
            Jp[(size_t)r * EDIM] = v;
        }
    }
}

extern "C" void kernel_launch(void* const* d_in, const int* in_sizes, int n_in,
                              void* d_out, int out_size, void* d_ws, size_t ws_size,
                              hipStream_t stream) {
    const float* y     = (const float*)d_in[0];
    const float* Ic    = (const float*)d_in[1];
    const float* C     = (const float*)d_in[2];
    const float* g_Na  = (const float*)d_in[3];
    const float* E_Na  = (const float*)d_in[4];
    const float* g_K   = (const float*)d_in[5];
    const float* E_K   = (const float*)d_in[6];
    const float* g_L   = (const float*)d_in[7];
    const float* E_L   = (const float*)d_in[8];
    const float* m_inf = (const float*)d_in[9];
    const float* tau_m = (const float*)d_in[10];
    const float* h_inf = (const float*)d_in[11];
    const float* tau_h = (const float*)d_in[12];
    const float* n_inf = (const float*)d_in[13];
    const float* tau_n = (const float*)d_in[14];
    const float* g_C   = (const float*)d_in[15];

    float* ydot = (float*)d_out;
    vf4*   J    = (vf4*)((float*)d_out + (size_t)BATCH * EDIM);

    hh_fused<<<BATCH, 512, 0, stream>>>(y, Ic, C, g_Na, E_Na, g_K, E_K, g_L, E_L,
                                        m_inf, tau_m, h_inf, tau_h, n_inf, tau_n,
                                        g_C, ydot, J);
}